// Round 1
// baseline (89.167 us; speedup 1.0000x reference)
//
#include <hip/hip_runtime.h>

// Problem constants (fixed by the reference):
//   x: (B=2, C=64, H=16, W=64) fp32; S = H*W = 1024; heads g=64, per-head c=1.
//   scores[s,t] = q_s * k_t / 8 ; softmax over t ; o_s = sum_t p_st * v_t
//
// Rank-1 trick (carried over): with c=1, o_s = f(p_s) with
//   f(p) = sum_t 2^(p k_t) v_t / sum_t 2^(p k_t),  p = q_s * (1/8) * log2(e)
// approximated by 16-node Chebyshev interpolation of numerator/denominator on
// the head's exact range [-pmax, pmax]. rel err ~1e-9 typ, ~1e-6 at 5-sigma.
//
// R(this): SINGLE-LAUNCH producer/consumer fusion.
//   Theory: timed region = ws-poison fill (~39.6us, harness, unremovable)
//   + 2 launch slots (~10-12us each) + ~15us work. The cross-kernel payload
//   is only 17KB of Chebyshev coeffs, not the 512KB O tensor -> fuse into one
//   kernel: blocks 0..127 produce per-head coeffs, blocks 128..255 consume
//   (eval + Wo projection + residual), handshaking through agent-scope
//   atomics in ws. Saves one launch slot + the O roundtrip, and consumer
//   x-staging/q-projection overlaps the producer phase.
//
//   Deadlock safety: __launch_bounds__(1024) => VGPR<=128 => 16 waves/CU
//   => every CU hosts >=1 block => capacity (256) >= grid (256): all blocks
//   co-resident whatever the dispatch order; producers are blockIdx 0..127
//   so they receive CUs first anyway.
//   Coherence: coeffs+flags use agent-scope atomics (device coherence point,
//   immune to per-XCD L2 non-coherence). Poison safety: MAGIC is not a
//   repeated-byte pattern; if the timing loop replays WITHOUT re-poisoning,
//   stale MAGIC flags skip the wait -- harmless, because coeffs are
//   bit-identical across replays (deterministic inputs).
//
// NOTE (R7 lesson, kept): hipLaunchCooperativeKernel costs ~+37us per graph
// replay on this harness -- this fusion uses a plain launch + capacity proof.
#define BB     2
#define CC     64
#define SS     1024
#define PSC    (0.125f * 1.44269504f)   // (1/sqrt(64)) * log2(e)
#define PI_F   3.14159265358979f
#define NCHEB  16
#define CSTRIDE 34                       // per-head coeff stride (floats)
#define STILE  16                        // consumer spatial tile
#define MAGIC  0x5F3C2B1Au

#if __has_builtin(__builtin_amdgcn_exp2f)
#define EXP2(x) __builtin_amdgcn_exp2f(x)   // bare v_exp_f32
#else
#define EXP2(x) exp2f(x)
#endif

// ws layout (floats): [0..128)   flags (as uint, one per head)
//                     [128..128+128*34) coeffs: head h -> base h*34:
//                        [0..16) cse, [16..32) csv, [32] pmax, [33] pad
__global__ __launch_bounds__(1024) void fused_attn_kernel(
    const float* __restrict__ x,
    const float* __restrict__ Wq, const float* __restrict__ bq,
    const float* __restrict__ Wk, const float* __restrict__ bk,
    const float* __restrict__ Wv, const float* __restrict__ bv,
    const float* __restrict__ Wo, const float* __restrict__ bo,
    float* __restrict__ out, float* __restrict__ ws)
{
    unsigned* flags  = (unsigned*)ws;        // [128]
    float*    coeffs = ws + 128;             // [128][CSTRIDE]

    const int tid  = threadIdx.x;            // [0,1024)
    const int lane = tid & 63;
    const int wv   = tid >> 6;               // wave id [0,16)

    __shared__ union {
        struct {                              // producer view (8.4 KB)
            float ks[SS], vs[SS];
            float wred[16];
            float Fse[NCHEB], Fsv[NCHEB];
        } p;
        struct {                              // consumer view (16.9 KB)
            float xs[CC][STILE];              // staged x tile (also residual)
            float cofs[CC * CSTRIDE];         // this batch's 64 heads' coeffs
            float Os[CC][STILE];              // attention output tile
        } c;
    } sm;

    if (blockIdx.x < 128) {
        // ================= PRODUCER: one head = (b, o) =================
        const int head = blockIdx.x;
        const int b    = head >> 6;
        const int o    = head & 63;

        // ---- P1: project q,k,v for position t = tid (q only for pmax)
        const float* __restrict__ wqp = Wq + o * CC;   // block-uniform -> s_load
        const float* __restrict__ wkp = Wk + o * CC;
        const float* __restrict__ wvp = Wv + o * CC;
        const float* __restrict__ xb  = x + b * CC * SS + tid;

        float qa = bq[o], ka = bk[o], va = bv[o];
        #pragma unroll 16
        for (int c = 0; c < CC; ++c) {
            const float xv = xb[c * SS];     // lane-consecutive -> coalesced
            qa = fmaf(wqp[c], xv, qa);
            ka = fmaf(wkp[c], xv, ka);
            va = fmaf(wvp[c], xv, va);
        }
        sm.p.ks[tid] = ka;
        sm.p.vs[tid] = va;
        const float p = qa * PSC;

        // pmax reduction: wave max of |p|, then 16 partials in LDS
        float am = fabsf(p);
        #pragma unroll
        for (int off = 32; off; off >>= 1)
            am = fmaxf(am, __shfl_xor(am, off, 64));
        if (lane == 0) sm.p.wred[wv] = am;
        __syncthreads();

        float pmax = sm.p.wred[0];
        #pragma unroll
        for (int i = 1; i < 16; ++i) pmax = fmaxf(pmax, sm.p.wred[i]);
        pmax = fmaxf(pmax, 1e-20f);          // degenerate all-zero-q guard

        // ---- P2: nodal sums; wave j owns Chebyshev node j
        const float pj = pmax * __cosf((2 * wv + 1) * (PI_F / (2 * NCHEB)));
        float se = 0.f, sv = 0.f;
        #pragma unroll
        for (int i = 0; i < 16; ++i) {
            const int t = lane + 64 * i;     // stride-1: LDS conflict-free
            const float e = EXP2(pj * sm.p.ks[t]);
            se += e;
            sv = fmaf(e, sm.p.vs[t], sv);
        }
        #pragma unroll
        for (int off = 32; off; off >>= 1) {
            se += __shfl_xor(se, off, 64);
            sv += __shfl_xor(sv, off, 64);
        }
        if (lane == 0) { sm.p.Fse[wv] = se; sm.p.Fsv[wv] = sv; }
        __syncthreads();

        // ---- P3: DCT -> Chebyshev coefficients, agent-scope stores to ws
        float* __restrict__ C = coeffs + head * CSTRIDE;
        if (tid < 2 * NCHEB) {
            const int  n  = tid & (NCHEB - 1);
            const bool fn = tid >= NCHEB;
            const float* __restrict__ F = fn ? sm.p.Fsv : sm.p.Fse;
            float acc = 0.f;
            #pragma unroll
            for (int j = 0; j < NCHEB; ++j)
                acc = fmaf(F[j], __cosf(n * (2 * j + 1) * (PI_F / (2 * NCHEB))), acc);
            acc *= (n == 0) ? (1.f / NCHEB) : (2.f / NCHEB);
            __hip_atomic_store(C + (fn ? NCHEB : 0) + n, acc,
                               __ATOMIC_RELAXED, __HIP_MEMORY_SCOPE_AGENT);
        }
        if (tid == 0)
            __hip_atomic_store(C + 32, pmax,
                               __ATOMIC_RELAXED, __HIP_MEMORY_SCOPE_AGENT);
        __syncthreads();                     // all coeff stores retired (vmcnt0)
        if (tid == 0)
            __hip_atomic_store(&flags[head], MAGIC,
                               __ATOMIC_RELEASE, __HIP_MEMORY_SCOPE_AGENT);
    } else {
        // ============ CONSUMER: one (b, 16-position s-tile) ============
        const int cid = blockIdx.x - 128;    // [0,128)
        const int b   = cid >> 6;
        const int s0  = (cid & 63) * STILE;
        const int o   = tid >> 4;            // output channel [0,64)
        const int si  = tid & 15;            // position within tile

        // ---- C1 (overlaps producer phase): stage x tile, compute q
        sm.c.xs[o][si] = x[(b * CC + o) * SS + s0 + si];  // c=o,col=si mapping
        __syncthreads();

        const float* __restrict__ wqo = Wq + o * CC;
        float q = bq[o];                     // same fmaf order as producer ->
        #pragma unroll 16                    // bit-identical q -> |u| <= 1
        for (int c = 0; c < CC; ++c)
            q = fmaf(wqo[c], sm.c.xs[c][si], q);

        // ---- C2: wait for this batch's 64 producers (wave 0 watches flags)
        if (tid < 64) {
            while (__hip_atomic_load(&flags[b * 64 + tid],
                                     __ATOMIC_ACQUIRE, __HIP_MEMORY_SCOPE_AGENT)
                   != MAGIC)
                __builtin_amdgcn_s_sleep(2);
        }
        __syncthreads();

        // ---- C3: stage the batch's coeffs (agent loads -> coherent)
        const float* __restrict__ gc = coeffs + b * 64 * CSTRIDE;
        for (int i = tid; i < 64 * CSTRIDE; i += 1024)
            sm.c.cofs[i] = __hip_atomic_load(gc + i,
                                             __ATOMIC_RELAXED, __HIP_MEMORY_SCOPE_AGENT);
        __syncthreads();

        // ---- C4: Clenshaw evaluation of both interpolants for head o
        const float* __restrict__ Ch = sm.c.cofs + o * CSTRIDE;
        const float pmax = Ch[32];
        const float u  = q * PSC / pmax;     // in [-1,1] by construction
        const float tu = 2.f * u;
        float b1 = 0.f, b2 = 0.f, d1 = 0.f, d2 = 0.f;
        #pragma unroll
        for (int n = NCHEB - 1; n >= 1; --n) {
            const float nb = fmaf(tu, b1, Ch[n] - b2);
            b2 = b1; b1 = nb;
            const float nd = fmaf(tu, d1, Ch[NCHEB + n] - d2);
            d2 = d1; d1 = nd;
        }
        const float fse = fmaf(u, b1, Ch[0] - b2);
        const float fsv = fmaf(u, d1, Ch[NCHEB] - d2);
        sm.c.Os[o][si] = fsv / fse;
        __syncthreads();

        // ---- C5: output projection + residual, straight to out
        const float* __restrict__ woo = Wo + o * CC;
        float acc = bo[o];
        #pragma unroll 16
        for (int c = 0; c < CC; ++c)
            acc = fmaf(woo[c], sm.c.Os[c][si], acc);
        out[(b * CC + o) * SS + s0 + si] = sm.c.xs[o][si] + acc;
    }
}

extern "C" void kernel_launch(void* const* d_in, const int* in_sizes, int n_in,
                              void* d_out, int out_size, void* d_ws, size_t ws_size,
                              hipStream_t stream) {
    const float* x  = (const float*)d_in[0];
    const float* Wq = (const float*)d_in[1];
    const float* bq = (const float*)d_in[2];
    const float* Wk = (const float*)d_in[3];
    const float* bk = (const float*)d_in[4];
    const float* Wv = (const float*)d_in[5];
    const float* bv = (const float*)d_in[6];
    const float* Wo = (const float*)d_in[7];
    const float* bo = (const float*)d_in[8];
    float* out = (float*)d_out;
    float* ws  = (float*)d_ws;               // 17.9 KB used (flags + coeffs)

    // Single plain launch: 128 producer blocks + 128 consumer blocks.
    fused_attn_kernel<<<256, 1024, 0, stream>>>(x, Wq, bq, Wk, bk, Wv, bv,
                                                Wo, bo, out, ws);
}